// Round 4
// baseline (230.808 us; speedup 1.0000x reference)
//
#include <hip/hip_runtime.h>
#include <cstdint>

#define N_IMG 32
#define C_IN 128
#define H_IN 56
#define W_IN 56
#define K_OUT 256
#define HW (H_IN * W_IN)            // 3136
#define M_TOTAL (N_IMG * HW)        // 100352
#define XP_H 58
#define XP_W 58
#define XP_ELEMS (N_IMG * XP_H * XP_W * C_IN)   // 13,778,944 bf16
#define WT_ELEMS (9 * K_OUT * C_IN)             // 294,912 bf16
#define NKT 36                      // K-tiles of 32: 9 rs positions x 4 c-chunks

typedef __bf16 bf16x8 __attribute__((ext_vector_type(8)));
typedef float f32x4 __attribute__((ext_vector_type(4)));

__device__ __align__(16) unsigned short g_xp[XP_ELEMS];  // padded NHWC bf16 input
__device__ __align__(16) unsigned short g_wt[WT_ELEMS];  // wt[rs][k][c] bf16 weights

static __device__ __forceinline__ unsigned short f2bf(float f) {
    unsigned int u = __builtin_bit_cast(unsigned int, f);
    u += 0x7fffu + ((u >> 16) & 1u);   // RNE
    return (unsigned short)(u >> 16);
}

// async global->LDS, 16 bytes per lane; LDS dest = wave-uniform base + lane*16
static __device__ __forceinline__ void async_copy16(const unsigned short* g, unsigned short* l) {
    auto gp = (const __attribute__((address_space(1))) unsigned int*)g;
    auto lp = (__attribute__((address_space(3))) unsigned int*)l;
    __builtin_amdgcn_global_load_lds(gp, lp, 16, 0, 0);
}

// ---------------- prep kernel 1: NCHW fp32 -> padded NHWC bf16 (+border zero) --
__global__ __launch_bounds__(256) void xpose_x(const float* __restrict__ x) {
    __shared__ float tile[C_IN * 57];     // [c][w] padded
    const int h = blockIdx.x;
    const int n = blockIdx.y;
    const int tid = threadIdx.x;

    if (tid < 32) {
        int col = (tid >> 4) * (XP_W - 1);          // 0 or 57
        int q = tid & 15;
        uint4* dst = (uint4*)(g_xp + ((size_t)(n * XP_H + h + 1) * XP_W + col) * C_IN) + q;
        *dst = uint4{0u, 0u, 0u, 0u};
    }
    if (h == 0 || h == H_IN - 1) {
        int hp = (h == 0) ? 0 : XP_H - 1;
        uint4* base = (uint4*)(g_xp + ((size_t)(n * XP_H + hp) * XP_W) * C_IN);
        for (int q = tid; q < (XP_W * C_IN) / 8; q += 256) base[q] = uint4{0u, 0u, 0u, 0u};
    }

#pragma unroll
    for (int i = 0; i < 28; i++) {
        int e = i * 256 + tid;
        int c = e / 56;
        int w = e - c * 56;
        tile[c * 57 + w] = x[((n * C_IN + c) * H_IN + h) * W_IN + w];
    }
    __syncthreads();
    unsigned int* outp = (unsigned int*)g_xp;
#pragma unroll
    for (int i = 0; i < 14; i++) {
        int u = i * 256 + tid;
        int w = u >> 6;
        int cp = u & 63;
        float a = tile[(2 * cp) * 57 + w];
        float b = tile[(2 * cp + 1) * 57 + w];
        unsigned int pk = (unsigned int)f2bf(a) | ((unsigned int)f2bf(b) << 16);
        int idx = ((n * XP_H + h + 1) * XP_W + (w + 1)) * C_IN + 2 * cp;
        outp[idx >> 1] = pk;
    }
}

// ---------------- prep kernel 2: OIHW fp32 -> wt[rs][k][c] bf16 ----------------
__global__ __launch_bounds__(256) void xpose_w(const float* __restrict__ w) {
    int e = blockIdx.x * 256 + threadIdx.x;
    int rr = e >> 15;
    int rem = e & 32767;
    int k = rem >> 7;
    int c = rem & 127;
    g_wt[e] = f2bf(w[(k * C_IN + c) * 9 + rr]);
}

// ---------------- main: implicit-GEMM, 256M x 128N tile, BK=32, 8 waves --------
// Occupancy-first design (round-2 post-mortem: 1 block/CU + 240 unified regs
// left every sync gap as bare pipe idle; MfmaUtil 21%). Now: acc 64 regs,
// LDS 48 KiB -> 2 blocks/CU (m114: co-resident blocks' MFMA covers the other
// block's barrier/stage gaps). 36 K-tiles of 32; 2 phases each:
//   Ph1: 12 ds_read (all A+B frags) ; barrier ; lgkmcnt(0) ; 8 MFMA ; barrier
//        (this barrier proves ALL waves' reads of buf b are done)
//   Ph2: stage tile t+2 -> buf b (3 loads) ; 8 MFMA ; vmcnt(3) ; barrier
// Loads never drain to 0 mid-loop (T4). XOR-swizzle via pre-swizzled source (T2).
__global__ __launch_bounds__(512, 4) void conv_main(float* __restrict__ out) {
    __shared__ __align__(16) unsigned short As[2][8192];   // [buf][256 rows x 32]
    __shared__ __align__(16) unsigned short Bs[2][4096];   // [buf][128 rows x 32]
    const unsigned short* __restrict__ xp = g_xp;
    const unsigned short* __restrict__ wt = g_wt;

    const int tid = threadIdx.x;
    const int wave = tid >> 6, lane = tid & 63;
    const int lr = lane & 15, lq = lane >> 4;
    const int wmL = (wave >> 1) * 64;   // wave m-offset (4 waves in M)
    const int wnL = (wave & 1) * 64;    // wave n-offset (2 waves in N)

    // XCD swizzle, bijective (784 = 8*98); (m-tile, k-half) pairs stay same-XCD
    const int bid = blockIdx.x;
    const int g = (bid & 7) * 98 + (bid >> 3);
    const int m0 = (g >> 1) * 256;
    const int k0 = (g & 1) * 128;

    // staging: A = 1024 units of 16B (u = j*512+tid), B = 512 units (u = tid).
    // unit u -> row=u>>2, seg=u&3; source col pre-swizzled seg^(row&3) so the
    // linear global_load_lds dest + swizzled ds_read form the same involution.
    int a_src[2], lds_a[2];
#pragma unroll
    for (int j = 0; j < 2; j++) {
        const int u = j * 512 + tid;
        const int row = u >> 2, seg = u & 3;
        const int sw = (seg ^ (row & 3)) * 8;
        int p = m0 + row;
        int n = p / HW;
        int rem = p - n * HW;
        int h = rem / W_IN;
        int w = rem - h * W_IN;
        a_src[j] = ((n * XP_H + h) * XP_W + w) * C_IN + sw;
        lds_a[j] = (j * 512 + wave * 64) * 8;   // wave-uniform; HW adds lane*16B
    }
    const int brow_s = tid >> 2, bseg = tid & 3;
    const int b_src = (k0 + brow_s) * C_IN + (bseg ^ (brow_s & 3)) * 8;
    const int lds_b = wave * 64 * 8;

    // ds_read swizzled column (shorts): logical seg lq, stored seg lq^(row&3)
    const int csw = (lq ^ (lr & 3)) * 8;

    // stage full K-tile kt (A 16KB + B 8KB) into buffer nb: 3 loads per thread
    auto stage_tile = [&](int kt, int nb) {
        const int rs = kt >> 2;
        const int r = (rs * 11) >> 5;            // rs/3
        const int sc = rs - r * 3;               // rs%3
        const int aoff = (r * XP_W + sc) * C_IN + (kt & 3) * 32;
        const int boff = rs * (K_OUT * C_IN) + (kt & 3) * 32;
#pragma unroll
        for (int j = 0; j < 2; j++)
            async_copy16(xp + a_src[j] + aoff, &As[nb][lds_a[j]]);
        async_copy16(wt + b_src + boff, &Bs[nb][lds_b]);
    };

    f32x4 acc[4][4];
#pragma unroll
    for (int mi = 0; mi < 4; mi++)
#pragma unroll
        for (int ni = 0; ni < 4; ni++) acc[mi][ni] = f32x4{0.f, 0.f, 0.f, 0.f};

    // prologue: t0 -> buf0, t1 -> buf1; in-order retire => vmcnt(3) means t0 in
    stage_tile(0, 0);
    stage_tile(1, 1);
    asm volatile("s_waitcnt vmcnt(3)" ::: "memory");
    __builtin_amdgcn_s_barrier();          // all waves' t0 loads landed
    asm volatile("" ::: "memory");

#pragma unroll 2
    for (int t = 0; t < NKT; ++t) {
        const int b = t & 1;
        bf16x8 af[4], bfv[4];

        // ---- Ph1: read all fragments of buf b; MFMA (ni 0-1) ----
#pragma unroll
        for (int mi = 0; mi < 4; mi++)
            af[mi] = *(const bf16x8*)(&As[b][(wmL + mi * 16 + lr) * 32 + csw]);
#pragma unroll
        for (int ni = 0; ni < 4; ni++)
            bfv[ni] = *(const bf16x8*)(&Bs[b][(wnL + ni * 16 + lr) * 32 + csw]);
        __builtin_amdgcn_s_barrier();
        asm volatile("s_waitcnt lgkmcnt(0)" ::: "memory");
        __builtin_amdgcn_sched_barrier(0);       // rule 18: pin MFMA below wait
        __builtin_amdgcn_s_setprio(1);
#pragma unroll
        for (int mi = 0; mi < 4; mi++)
#pragma unroll
            for (int ni = 0; ni < 2; ni++)
                acc[mi][ni] = __builtin_amdgcn_mfma_f32_16x16x32_bf16(
                    af[mi], bfv[ni], acc[mi][ni], 0, 0, 0);
        __builtin_amdgcn_s_setprio(0);
        __builtin_amdgcn_s_barrier();       // ALL waves done reading buf b
        asm volatile("" ::: "memory");

        // ---- Ph2: stage t+2 into buf b (now safe); MFMA (ni 2-3) ----
        if (t + 2 < NKT) stage_tile(t + 2, b);
        __builtin_amdgcn_s_setprio(1);
#pragma unroll
        for (int mi = 0; mi < 4; mi++)
#pragma unroll
            for (int ni = 2; ni < 4; ni++)
                acc[mi][ni] = __builtin_amdgcn_mfma_f32_16x16x32_bf16(
                    af[mi], bfv[ni], acc[mi][ni], 0, 0, 0);
        __builtin_amdgcn_s_setprio(0);
        // retire tile t+1 (issued 2 phases ago); keep t+2's 3 loads in flight
        if (t + 2 < NKT) {
            asm volatile("s_waitcnt vmcnt(3)" ::: "memory");
        } else {
            asm volatile("s_waitcnt vmcnt(0)" ::: "memory");
        }
        __builtin_amdgcn_s_barrier();
        asm volatile("" ::: "memory");
    }

    // epilogue: lane's float4 = 4 consecutive pixels at fixed out-channel k
#pragma unroll
    for (int mi = 0; mi < 4; mi++) {
        int p = m0 + wmL + mi * 16 + lq * 4;   // mult of 4; 3136%4==0 -> same n
        int n = p / HW;
        int off = p - n * HW;
#pragma unroll
        for (int ni = 0; ni < 4; ni++) {
            int k = k0 + wnL + ni * 16 + lr;
            *(f32x4*)(out + (n * K_OUT + k) * HW + off) = acc[mi][ni];
        }
    }
}

extern "C" void kernel_launch(void* const* d_in, const int* in_sizes, int n_in,
                              void* d_out, int out_size, void* d_ws, size_t ws_size,
                              hipStream_t stream) {
    const float* x = (const float*)d_in[0];
    const float* w = (const float*)d_in[1];
    float* out = (float*)d_out;

    hipLaunchKernelGGL(xpose_x, dim3(H_IN, N_IMG), dim3(256), 0, stream, x);
    hipLaunchKernelGGL(xpose_w, dim3(WT_ELEMS / 256), dim3(256), 0, stream, w);
    hipLaunchKernelGGL(conv_main, dim3((M_TOTAL / 256) * (K_OUT / 128)), dim3(512), 0, stream, out);
}